// Round 13
// baseline (135.541 us; speedup 1.0000x reference)
//
#include <hip/hip_runtime.h>
#include <stdint.h>

#define B_DIM 16384
#define L_DIM 4096
#define H_DIM 256
#define LN_EPS 1e-5f
// bijective 4-bit slot permutation from the low 4 row bits
#define PERM4(r) ((((r) & 7) << 1) | (((r) >> 3) & 1))

typedef unsigned short u16;
typedef __attribute__((ext_vector_type(4))) float f32x4;
typedef __attribute__((ext_vector_type(8))) short short8;

__device__ __forceinline__ u16 f2bf(float f) {
  union { float f; uint32_t u; } v; v.f = f;
  uint32_t u = v.u;
  u += 0x7FFFu + ((u >> 16) & 1u);   // round-to-nearest-even
  return (u16)(u >> 16);
}

__device__ __forceinline__ short8 cvt8(const float4& u, const float4& v) {
  short8 o;
  o[0] = (short)f2bf(u.x); o[1] = (short)f2bf(u.y);
  o[2] = (short)f2bf(u.z); o[3] = (short)f2bf(u.w);
  o[4] = (short)f2bf(v.x); o[5] = (short)f2bf(v.y);
  o[6] = (short)f2bf(v.z); o[7] = (short)f2bf(v.w);
  return o;
}

__device__ __forceinline__ void gload_lds16(const void* g, void* l) {
  __builtin_amdgcn_global_load_lds((const __attribute__((address_space(1))) void*)g,
                                   (__attribute__((address_space(3))) void*)l, 16, 0, 0);
}

// Fragment-major prep (gathered emb / plain W1):
// frag = kstep*16 + nt;  dst[frag][lane][j] = bf16(src[row][nt*16 + (lane&15)])
// row = idx ? idx[kstep*32 + (lane>>4)*8 + j] : (kstep*32 + (lane>>4)*8 + j)
__global__ __launch_bounds__(256) void prep_frag(const float* __restrict__ src,
                                                 const int* __restrict__ idx,
                                                 u16* __restrict__ dst) {
  const int t = threadIdx.x;
  const int l = t & 63;
  const int w = t >> 6;
  const int frag = blockIdx.x * 4 + w;
  const int kstep = frag >> 4;
  const int nt = frag & 15;
  const int n = nt * 16 + (l & 15);
  const int kbase = kstep * 32 + (l >> 4) * 8;
  short8 v;
#pragma unroll
  for (int j = 0; j < 8; ++j) {
    const int k = kbase + j;
    const int g = idx ? idx[k] : k;
    v[j] = (short)f2bf(src[(size_t)g * H_DIM + n]);
  }
  *reinterpret_cast<short8*>(dst + ((size_t)frag * 64 + l) * 8) = v;
}

// Fused: h = x @ feat (bf16 MFMA, K=4096), then out = LN(relu(h @ W1 + b1)).
// BM=64 (halves per-block fragB rereads: 512 blocks->256, 1GB->512MB L2
// traffic -- R7/R11/R12 all ~105us proved BM=32's B-traffic is the limiter).
// 512 thr = 8 waves; wave owns all 64 rows x its 32 cols (acc[4][2]).
// B: register dbuf via coalesced fragment-major loads -- SELF-TIMED, never in
// the barrier-coupled drain (R2/R6/R8's 1-block/CU failures all drained full
// 32-40KB gload_lds staging per stage; here the drained set is A only).
// A: gload_lds depth-2 (3 bufs, issued 2 stages ahead), counted vmcnt(6) at
// stage top (issue order pinned [B group][A group] by sched_barrier(0); at
// top of S outstanding = A(S):2,B(S):4,A(S+1):2 -> all-but-6 = A(S) landed;
// S=63: vmcnt(4)). Two-barrier skeleton kept verbatim (R9 single-barrier
// rejected). grid 256, 1 block/CU, LDS 68KB.
__global__ __launch_bounds__(512, 2) void fused(const float* __restrict__ x,
                                                const u16* __restrict__ fragB,
                                                const u16* __restrict__ fragW,
                                                const float* __restrict__ b1,
                                                const float* __restrict__ gmm,
                                                const float* __restrict__ bta,
                                                float* __restrict__ out) {
  // main: A 3x16KB @0. gemm2 (time-separated): h-tile 32KB @0, W dbuf 2x16KB
  // @32K, lnred 4KB @64K.
  __shared__ __align__(16) char pool[69632];
  const int t = threadIdx.x;
  const int l = t & 63;
  const int wv = t >> 6;                 // 0..7 : col group (32 cols)
  const int m0 = blockIdx.x * 64;
  const float* xbase = x + (size_t)m0 * L_DIM;

  f32x4 acc[4][2] = {};
  short8 bP[4], bQ[4];

  // ---- prologue: A(0)->buf0, A(1)->buf1, B(0)->bP (order pinned) ----
#pragma unroll
  for (int i = 0; i < 2; ++i) {
    const int R = (wv * 2 + i) * 4 + (l >> 4);           // rows 0..63
    const int c16 = (l & 15) ^ PERM4(R);
    gload_lds16(xbase + (size_t)R * L_DIM + c16 * 4, pool + (wv * 2 + i) * 1024);
  }
  __builtin_amdgcn_sched_barrier(0);
#pragma unroll
  for (int i = 0; i < 2; ++i) {
    const int R = (wv * 2 + i) * 4 + (l >> 4);
    const int c16 = (l & 15) ^ PERM4(R);
    gload_lds16(xbase + (size_t)R * L_DIM + 64 + c16 * 4,
                pool + 16384 + (wv * 2 + i) * 1024);
  }
  __builtin_amdgcn_sched_barrier(0);
#pragma unroll
  for (int f = 0; f < 4; ++f) {                          // f = ks*2 + ntl
    const int frag = (f >> 1) * 16 + wv * 2 + (f & 1);
    bP[f] = *(const short8*)(fragB + (size_t)frag * 512 + l * 8);
  }
  __builtin_amdgcn_sched_barrier(0);

  // two-barrier stage; compute from cur B regs + LDS A buf S%3
  auto stage = [&](int S, short8 (&cur)[4], short8 (&nxt)[4]) {
    if (S == 63) asm volatile("s_waitcnt vmcnt(4)" ::: "memory");
    else         asm volatile("s_waitcnt vmcnt(6)" ::: "memory");
    __builtin_amdgcn_s_barrier();
    __builtin_amdgcn_sched_barrier(0);
    if (S < 63) {                                        // B(S+1) -> nxt regs
#pragma unroll
      for (int f = 0; f < 4; ++f) {
        const int frag = (2 * (S + 1) + (f >> 1)) * 16 + wv * 2 + (f & 1);
        nxt[f] = *(const short8*)(fragB + (size_t)frag * 512 + l * 8);
      }
    }
    __builtin_amdgcn_sched_barrier(0);                   // pin: B before A
    if (S < 62) {                                        // A(S+2) -> buf (S+2)%3
#pragma unroll
      for (int i = 0; i < 2; ++i) {
        const int R = (wv * 2 + i) * 4 + (l >> 4);
        const int c16 = (l & 15) ^ PERM4(R);
        gload_lds16(xbase + (size_t)R * L_DIM + (S + 2) * 64 + c16 * 4,
                    pool + ((S + 2) % 3) * 16384 + (wv * 2 + i) * 1024);
      }
    }
    __builtin_amdgcn_sched_barrier(0);                   // pin: issues before compute
    const char* bA = pool + (S % 3) * 16384;
#pragma unroll
    for (int ks = 0; ks < 2; ++ks) {
      short8 af[4];
#pragma unroll
      for (int mi = 0; mi < 4; ++mi) {
        const int row = mi * 16 + (l & 15);
        const int p4 = PERM4(row);
        const int gs = ks * 8 + (l >> 4) * 2;
        const float4 a0 = *(const float4*)(bA + row * 256 + ((gs ^ p4) * 16));
        const float4 a1 = *(const float4*)(bA + row * 256 + (((gs + 1) ^ p4) * 16));
        af[mi] = cvt8(a0, a1);
      }
#pragma unroll
      for (int ntl = 0; ntl < 2; ++ntl)
#pragma unroll
        for (int mi = 0; mi < 4; ++mi)
          acc[mi][ntl] = __builtin_amdgcn_mfma_f32_16x16x32_bf16(
              af[mi], cur[ks * 2 + ntl], acc[mi][ntl], 0, 0, 0);
    }
    asm volatile("s_waitcnt lgkmcnt(0)" ::: "memory");   // A reads done pre-overwrite
    __builtin_amdgcn_s_barrier();
  };

  for (int sp = 0; sp < 32; ++sp) {                      // P/Q static alternation
    stage(sp * 2,     bP, bQ);
    stage(sp * 2 + 1, bQ, bP);
  }

  // ---- GEMM2: issue W(0); write h tile (A pool dead after final barrier) ----
#pragma unroll
  for (int i = 0; i < 2; ++i) {                          // W(0): 16 frags total
    const int j = wv * 2 + i;
    gload_lds16(fragW + (size_t)j * 512 + l * 8, pool + 32768 + j * 1024);
  }
  // h tile bf16 @pool[0..32K): row*512 + ((col>>3)^(row&15))*16 + (col&7)*2
#pragma unroll
  for (int mi = 0; mi < 4; ++mi)
#pragma unroll
    for (int rr = 0; rr < 4; ++rr) {
      const int row = mi * 16 + (l >> 4) * 4 + rr;
#pragma unroll
      for (int ntl = 0; ntl < 2; ++ntl) {
        const int col = wv * 32 + ntl * 16 + (l & 15);
        const int ls = (col >> 3) ^ (row & 15);
        *(u16*)(pool + row * 512 + ls * 16 + (col & 7) * 2) = f2bf(acc[mi][ntl][rr]);
      }
    }
  asm volatile("s_waitcnt lgkmcnt(0)" ::: "memory");
  __builtin_amdgcn_s_barrier();

  f32x4 acc2[4][2] = {};
  for (int kt = 0; kt < 8; ++kt) {
    asm volatile("s_waitcnt vmcnt(0)" ::: "memory");     // W(kt) landed
    __builtin_amdgcn_s_barrier();
    __builtin_amdgcn_sched_barrier(0);
    if (kt < 7) {
      const u16* srcW = fragW + (size_t)(kt + 1) * 16 * 512;
      char* dstW = pool + 32768 + ((kt + 1) & 1) * 16384;
#pragma unroll
      for (int i = 0; i < 2; ++i) {
        const int j = wv * 2 + i;
        gload_lds16(srcW + (size_t)j * 512 + l * 8, dstW + j * 1024);
      }
    }
    __builtin_amdgcn_sched_barrier(0);
    const char* bW = pool + 32768 + (kt & 1) * 16384;
    short8 af[4];
#pragma unroll
    for (int mi = 0; mi < 4; ++mi) {
      const int row = mi * 16 + (l & 15);
      af[mi] = *(const short8*)(pool + row * 512 +
                                (((kt * 4 + (l >> 4)) ^ (row & 15)) << 4));
    }
#pragma unroll
    for (int ntl = 0; ntl < 2; ++ntl) {
      const short8 bfv = *(const short8*)(bW + (wv * 2 + ntl) * 1024 + l * 16);
#pragma unroll
      for (int mi = 0; mi < 4; ++mi)
        acc2[mi][ntl] = __builtin_amdgcn_mfma_f32_16x16x32_bf16(af[mi], bfv, acc2[mi][ntl], 0, 0, 0);
    }
    asm volatile("s_waitcnt lgkmcnt(0)" ::: "memory");
    __builtin_amdgcn_s_barrier();
  }

  // ---- bias + relu + LN + store ----
  float bv[2], gg[2], bb[2];
#pragma unroll
  for (int ntl = 0; ntl < 2; ++ntl) {
    const int col = wv * 32 + ntl * 16 + (l & 15);
    bv[ntl] = b1[col]; gg[ntl] = gmm[col]; bb[ntl] = bta[col];
  }
  float* lnred = (float*)(pool + 65536);   // [8 wv][64 rows][2] = 4KB
#pragma unroll
  for (int mi = 0; mi < 4; ++mi)
#pragma unroll
    for (int rr = 0; rr < 4; ++rr) {
      float s = 0.f, q = 0.f;
#pragma unroll
      for (int ntl = 0; ntl < 2; ++ntl) {
        const float v = fmaxf(acc2[mi][ntl][rr] + bv[ntl], 0.f);
        acc2[mi][ntl][rr] = v; s += v; q += v * v;
      }
#pragma unroll
      for (int m = 1; m < 16; m <<= 1) { s += __shfl_xor(s, m); q += __shfl_xor(q, m); }
      if ((l & 15) == 0) {
        const int row = mi * 16 + (l >> 4) * 4 + rr;
        lnred[(wv * 64 + row) * 2 + 0] = s;
        lnred[(wv * 64 + row) * 2 + 1] = q;
      }
    }
  __syncthreads();
#pragma unroll
  for (int mi = 0; mi < 4; ++mi)
#pragma unroll
    for (int rr = 0; rr < 4; ++rr) {
      const int row = mi * 16 + (l >> 4) * 4 + rr;
      float S = 0.f, Q = 0.f;
#pragma unroll
      for (int w2 = 0; w2 < 8; ++w2) {
        S += lnred[(w2 * 64 + row) * 2 + 0];
        Q += lnred[(w2 * 64 + row) * 2 + 1];
      }
      const float mu = S * (1.0f / 256.0f);
      const float rstd = rsqrtf(Q * (1.0f / 256.0f) - mu * mu + LN_EPS);
      float* op = out + (size_t)(m0 + row) * H_DIM;
#pragma unroll
      for (int ntl = 0; ntl < 2; ++ntl) {
        const int col = wv * 32 + ntl * 16 + (l & 15);
        op[col] = gg[ntl] * (acc2[mi][ntl][rr] - mu) * rstd + bb[ntl];
      }
    }
}

extern "C" void kernel_launch(void* const* d_in, const int* in_sizes, int n_in,
                              void* d_out, int out_size, void* d_ws, size_t ws_size,
                              hipStream_t stream) {
  const float* x    = (const float*)d_in[0];
  const float* emb  = (const float*)d_in[1];
  const float* W1   = (const float*)d_in[2];
  const float* b1   = (const float*)d_in[3];
  const float* gmm  = (const float*)d_in[4];
  const float* bta  = (const float*)d_in[5];
  const int*   gidx = (const int*)d_in[6];
  float* out = (float*)d_out;

  char* ws = (char*)d_ws;
  u16* fragB = (u16*)ws;                                   // [128 ksteps][16 nt][64][8] = 2 MB
  u16* fragW = (u16*)(ws + (size_t)H_DIM * L_DIM * 2);     // [8 ksteps][16 nt][64][8] = 128 KB

  prep_frag<<<512, 256, 0, stream>>>(emb, gidx, fragB);    // 2048 frags
  prep_frag<<<32, 256, 0, stream>>>(W1, nullptr, fragW);   // 128 frags
  fused<<<256, 512, 0, stream>>>(x, fragB, fragW, b1, gmm, bta, out);
}

// Round 14
// 109.929 us; speedup vs baseline: 1.2330x; 1.2330x over previous
//
#include <hip/hip_runtime.h>
#include <stdint.h>

#define B_DIM 16384
#define L_DIM 4096
#define H_DIM 256
#define LN_EPS 1e-5f
// bijective 4-bit slot permutation from the low 4 row bits
#define PERM4(r) ((((r) & 7) << 1) | (((r) >> 3) & 1))

typedef unsigned short u16;
typedef __attribute__((ext_vector_type(4))) float f32x4;
typedef __attribute__((ext_vector_type(8))) short short8;

__device__ __forceinline__ u16 f2bf(float f) {
  union { float f; uint32_t u; } v; v.f = f;
  uint32_t u = v.u;
  u += 0x7FFFu + ((u >> 16) & 1u);   // round-to-nearest-even
  return (u16)(u >> 16);
}

__device__ __forceinline__ short8 cvt8(const float4& u, const float4& v) {
  short8 o;
  o[0] = (short)f2bf(u.x); o[1] = (short)f2bf(u.y);
  o[2] = (short)f2bf(u.z); o[3] = (short)f2bf(u.w);
  o[4] = (short)f2bf(v.x); o[5] = (short)f2bf(v.y);
  o[6] = (short)f2bf(v.z); o[7] = (short)f2bf(v.w);
  return o;
}

__device__ __forceinline__ void gload_lds16(const void* g, void* l) {
  __builtin_amdgcn_global_load_lds((const __attribute__((address_space(1))) void*)g,
                                   (__attribute__((address_space(3))) void*)l, 16, 0, 0);
}

// Fragment-major prep (gathered emb / plain W1):
// frag = kstep*16 + nt;  dst[frag][lane][j] = bf16(src[row][nt*16 + (lane&15)])
// row = idx ? idx[kstep*32 + (lane>>4)*8 + j] : (kstep*32 + (lane>>4)*8 + j)
__global__ __launch_bounds__(256) void prep_frag(const float* __restrict__ src,
                                                 const int* __restrict__ idx,
                                                 u16* __restrict__ dst) {
  const int t = threadIdx.x;
  const int l = t & 63;
  const int w = t >> 6;
  const int frag = blockIdx.x * 4 + w;
  const int kstep = frag >> 4;
  const int nt = frag & 15;
  const int n = nt * 16 + (l & 15);
  const int kbase = kstep * 32 + (l >> 4) * 8;
  short8 v;
#pragma unroll
  for (int j = 0; j < 8; ++j) {
    const int k = kbase + j;
    const int g = idx ? idx[k] : k;
    v[j] = (short)f2bf(src[(size_t)g * H_DIM + n]);
  }
  *reinterpret_cast<short8*>(dst + ((size_t)frag * 64 + l) * 8) = v;
}

// Fused: h = x @ feat (bf16 MFMA, K=4096), then out = LN(relu(h @ W1 + b1)).
// R14 EXPERIMENT: wave-TLP. Same R12 skeleton/maps/sync, but 512 thr = 8 waves
// (wave = 32 rows x 32 cols, acc[2][2]); BM=32, grid 512 -> 2 blocks/CU, now
// 16 waves/CU = 4 contexts/SIMD (was 2). Rationale: R7/R11/R12 (~105us) have
// wildly different stage CONTENT but identical skeleton and identical time;
// R13 warm replays (all data L3-resident) ran the same 163us -> not traffic-
// bound anywhere; per-stage time is convoy/latency exposure that 2 wave
// contexts per SIMD cannot fill. VGPR must stay <=128 for 16 waves/CU:
// __launch_bounds__(512,4) (R12 was 88 VGPR; B dbuf here is 64).
// A: R12's exact gload_lds dbuf + PERM4 swizzle (f32). B: register dbuf via
// coalesced fragment-major loads (self-timed). Sync: two-barrier stage,
// vmcnt(0) only (counted-vmcnt and single-barrier variants failed R4/R9).
__global__ __launch_bounds__(512, 4) void fused(const float* __restrict__ x,
                                                const u16* __restrict__ fragB,
                                                const u16* __restrict__ fragW,
                                                const float* __restrict__ b1,
                                                const float* __restrict__ gmm,
                                                const float* __restrict__ bta,
                                                float* __restrict__ out) {
  // main: A dbuf 2x8KB @0. gemm2 (time-separated): h-tile 16KB @0 (reuses A),
  // W dbuf 2x16KB @16K, lnred 2KB @49152. Total 51200 -> 2 blocks/CU.
  __shared__ __align__(16) char pool[51200];
  const int t = threadIdx.x;
  const int l = t & 63;
  const int wv = t >> 6;                 // 0..7 : col group (32 cols)
  const int m0 = blockIdx.x * 32;
  const float* xbase = x + (size_t)m0 * L_DIM;

  f32x4 acc[2][2] = {};
  short8 bP[4], bQ[4];

  // A staging map (one gload_lds per thread per stage): chunk = wv,
  // R = wv*4 + (l>>4) covers rows 0..31, source col16 pre-PERM4-swizzled.
  const int Rst = wv * 4 + (l >> 4);
  const int c16 = (l & 15) ^ PERM4(Rst);
  const float* asrc = xbase + (size_t)Rst * L_DIM + c16 * 4;

  // ---- prologue: issue A(0); load B(0) -> bP ----
  gload_lds16(asrc, pool + wv * 1024);
#pragma unroll
  for (int f = 0; f < 4; ++f) {                          // f = ks*2 + ntl
    const int frag = (f >> 1) * 16 + wv * 2 + (f & 1);
    bP[f] = *(const short8*)(fragB + (size_t)frag * 512 + l * 8);
  }

  // two-barrier stage (R7/R12-proven sync structure, unchanged)
  auto stage = [&](int S, short8 (&cur)[4], short8 (&nxt)[4]) {
    asm volatile("s_waitcnt vmcnt(0)" ::: "memory");     // A(S) in LDS, B(S) in regs
    __builtin_amdgcn_s_barrier();
    __builtin_amdgcn_sched_barrier(0);
    if (S < 63) {
      // issue A(S+1) -> LDS buf (S+1)&1
      gload_lds16(asrc + (S + 1) * 64, pool + ((S + 1) & 1) * 8192 + wv * 1024);
      // B(S+1) -> nxt regs (coalesced fragment-major, self-timed)
#pragma unroll
      for (int f = 0; f < 4; ++f) {
        const int frag = (2 * (S + 1) + (f >> 1)) * 16 + wv * 2 + (f & 1);
        nxt[f] = *(const short8*)(fragB + (size_t)frag * 512 + l * 8);
      }
    }
    __builtin_amdgcn_sched_barrier(0);                   // pin issues before compute
    const char* bA = pool + (S & 1) * 8192;
#pragma unroll
    for (int ks = 0; ks < 2; ++ks) {
      short8 af[2];
#pragma unroll
      for (int mi = 0; mi < 2; ++mi) {
        const int row = mi * 16 + (l & 15);
        const int p4 = PERM4(row);
        const int gs = ks * 8 + (l >> 4) * 2;
        const float4 a0 = *(const float4*)(bA + row * 256 + ((gs ^ p4) * 16));
        const float4 a1 = *(const float4*)(bA + row * 256 + (((gs + 1) ^ p4) * 16));
        af[mi] = cvt8(a0, a1);
      }
#pragma unroll
      for (int ntl = 0; ntl < 2; ++ntl)
#pragma unroll
        for (int mi = 0; mi < 2; ++mi)
          acc[mi][ntl] = __builtin_amdgcn_mfma_f32_16x16x32_bf16(
              af[mi], cur[ks * 2 + ntl], acc[mi][ntl], 0, 0, 0);
    }
    asm volatile("s_waitcnt lgkmcnt(0)" ::: "memory");   // A reads done pre-overwrite
    __builtin_amdgcn_s_barrier();
  };

  for (int sp = 0; sp < 32; ++sp) {                      // P/Q static alternation
    stage(sp * 2,     bP, bQ);
    stage(sp * 2 + 1, bQ, bP);
  }

  // ---- GEMM2: issue W(0); write h tile into [0,16K) (A region dead) ----
#pragma unroll
  for (int i = 0; i < 2; ++i) {                          // W(0): 16 frags, 8 waves x 2
    const int j = wv * 2 + i;
    gload_lds16(fragW + (size_t)j * 512 + l * 8, pool + 16384 + j * 1024);
  }
  // h tile bf16: row*512 + ((col>>3)^(row&15))*16 + (col&7)*2   (R12/R13 map)
#pragma unroll
  for (int mi = 0; mi < 2; ++mi)
#pragma unroll
    for (int rr = 0; rr < 4; ++rr) {
      const int row = mi * 16 + (l >> 4) * 4 + rr;
#pragma unroll
      for (int ntl = 0; ntl < 2; ++ntl) {
        const int col = wv * 32 + ntl * 16 + (l & 15);
        const int ls = (col >> 3) ^ (row & 15);
        *(u16*)(pool + row * 512 + ls * 16 + (col & 7) * 2) = f2bf(acc[mi][ntl][rr]);
      }
    }
  asm volatile("s_waitcnt lgkmcnt(0)" ::: "memory");
  __builtin_amdgcn_s_barrier();

  f32x4 acc2[2][2] = {};
  for (int kt = 0; kt < 8; ++kt) {
    asm volatile("s_waitcnt vmcnt(0)" ::: "memory");     // W(kt) landed
    __builtin_amdgcn_s_barrier();
    __builtin_amdgcn_sched_barrier(0);
    if (kt < 7) {
      const u16* srcW = fragW + (size_t)(kt + 1) * 16 * 512;
      char* dstW = pool + 16384 + ((kt + 1) & 1) * 16384;
#pragma unroll
      for (int i = 0; i < 2; ++i) {
        const int j = wv * 2 + i;
        gload_lds16(srcW + (size_t)j * 512 + l * 8, dstW + j * 1024);
      }
    }
    __builtin_amdgcn_sched_barrier(0);
    const char* bW = pool + 16384 + (kt & 1) * 16384;
    short8 af[2];
#pragma unroll
    for (int mi = 0; mi < 2; ++mi) {
      const int row = mi * 16 + (l & 15);
      af[mi] = *(const short8*)(pool + row * 512 +
                                (((kt * 4 + (l >> 4)) ^ (row & 15)) << 4));
    }
#pragma unroll
    for (int ntl = 0; ntl < 2; ++ntl) {
      const short8 bfv = *(const short8*)(bW + (wv * 2 + ntl) * 1024 + l * 16);
#pragma unroll
      for (int mi = 0; mi < 2; ++mi)
        acc2[mi][ntl] = __builtin_amdgcn_mfma_f32_16x16x32_bf16(af[mi], bfv, acc2[mi][ntl], 0, 0, 0);
    }
    asm volatile("s_waitcnt lgkmcnt(0)" ::: "memory");
    __builtin_amdgcn_s_barrier();
  }

  // ---- bias + relu + LN + store (R13's 8-wave reduce, 32 rows) ----
  float bv[2], gg[2], bb[2];
#pragma unroll
  for (int ntl = 0; ntl < 2; ++ntl) {
    const int col = wv * 32 + ntl * 16 + (l & 15);
    bv[ntl] = b1[col]; gg[ntl] = gmm[col]; bb[ntl] = bta[col];
  }
  float* lnred = (float*)(pool + 49152);   // [8 wv][32 rows][2] = 2KB
#pragma unroll
  for (int mi = 0; mi < 2; ++mi)
#pragma unroll
    for (int rr = 0; rr < 4; ++rr) {
      float s = 0.f, q = 0.f;
#pragma unroll
      for (int ntl = 0; ntl < 2; ++ntl) {
        const float v = fmaxf(acc2[mi][ntl][rr] + bv[ntl], 0.f);
        acc2[mi][ntl][rr] = v; s += v; q += v * v;
      }
#pragma unroll
      for (int m = 1; m < 16; m <<= 1) { s += __shfl_xor(s, m); q += __shfl_xor(q, m); }
      if ((l & 15) == 0) {
        const int row = mi * 16 + (l >> 4) * 4 + rr;
        lnred[(wv * 32 + row) * 2 + 0] = s;
        lnred[(wv * 32 + row) * 2 + 1] = q;
      }
    }
  __syncthreads();
#pragma unroll
  for (int mi = 0; mi < 2; ++mi)
#pragma unroll
    for (int rr = 0; rr < 4; ++rr) {
      const int row = mi * 16 + (l >> 4) * 4 + rr;
      float S = 0.f, Q = 0.f;
#pragma unroll
      for (int w2 = 0; w2 < 8; ++w2) {
        S += lnred[(w2 * 32 + row) * 2 + 0];
        Q += lnred[(w2 * 32 + row) * 2 + 1];
      }
      const float mu = S * (1.0f / 256.0f);
      const float rstd = rsqrtf(Q * (1.0f / 256.0f) - mu * mu + LN_EPS);
      float* op = out + (size_t)(m0 + row) * H_DIM;
#pragma unroll
      for (int ntl = 0; ntl < 2; ++ntl) {
        const int col = wv * 32 + ntl * 16 + (l & 15);
        op[col] = gg[ntl] * (acc2[mi][ntl][rr] - mu) * rstd + bb[ntl];
      }
    }
}

extern "C" void kernel_launch(void* const* d_in, const int* in_sizes, int n_in,
                              void* d_out, int out_size, void* d_ws, size_t ws_size,
                              hipStream_t stream) {
  const float* x    = (const float*)d_in[0];
  const float* emb  = (const float*)d_in[1];
  const float* W1   = (const float*)d_in[2];
  const float* b1   = (const float*)d_in[3];
  const float* gmm  = (const float*)d_in[4];
  const float* bta  = (const float*)d_in[5];
  const int*   gidx = (const int*)d_in[6];
  float* out = (float*)d_out;

  char* ws = (char*)d_ws;
  u16* fragB = (u16*)ws;                                   // [128 ksteps][16 nt][64][8] = 2 MB
  u16* fragW = (u16*)(ws + (size_t)H_DIM * L_DIM * 2);     // [8 ksteps][16 nt][64][8] = 128 KB

  prep_frag<<<512, 256, 0, stream>>>(emb, gidx, fragB);    // 2048 frags
  prep_frag<<<32, 256, 0, stream>>>(W1, nullptr, fragW);   // 128 frags
  fused<<<512, 512, 0, stream>>>(x, fragB, fragW, b1, gmm, bta, out);
}